// Round 1
// baseline (184.563 us; speedup 1.0000x reference)
//
#include <hip/hip_runtime.h>

#define MDIM 512
#define LDIM 31
#define WDIM 542            // MDIM + LDIM - 1
#define BDIM 4
#define ROW_IN (MDIM*LDIM)  // 15872 floats per (b,r) row
#define NROWS (BDIM*MDIM)   // 2048

__device__ __forceinline__ float wave_max(float v) {
    #pragma unroll
    for (int off = 32; off > 0; off >>= 1)
        v = fmaxf(v, __shfl_xor(v, off));
    return v;
}

__device__ __forceinline__ float sigmoid10(float h) {
    return 1.0f / (1.0f + __expf(-10.0f * h));
}

__global__ void kInit(unsigned int* g) {
    if (threadIdx.x < 2) g[threadIdx.x] = 0u;
}

// One block per (b, r) row. Computes y_raw -> d_out y-slot (unnormalized),
// and reduces global max(y_raw), max(Z) via atomicMax on float bits (all >= 0).
__global__ __launch_bounds__(256) void kA(const float* __restrict__ inp,
                                          const float* __restrict__ H,
                                          float* __restrict__ y_out,
                                          unsigned int* __restrict__ gmax) {
    __shared__ __align__(16) float s_in[ROW_IN];   // 63488 B
    __shared__ float s_hs[MDIM];                   // 2048 B
    __shared__ float s_y[WDIM];                    // 2168 B
    __shared__ float s_red[8];

    const int br  = blockIdx.x;          // b*512 + r
    const int r   = br & (MDIM - 1);
    const int tid = threadIdx.x;

    // stage input row (coalesced float4)
    const float4* src4 = (const float4*)(inp + (size_t)br * ROW_IN);
    float4* dst4 = (float4*)s_in;
    for (int t = tid; t < ROW_IN / 4; t += 256) dst4[t] = src4[t];

    // Hs row
    const float* hrow = H + (size_t)r * MDIM;
    for (int t = tid; t < MDIM; t += 256) s_hs[t] = sigmoid10(hrow[t]);
    __syncthreads();

    // y_raw[c] = sum_{m} Hs[m] * (0.25*in[m][i-1] + 0.5*in[m][i] + 0.25*in[m][i+1]), i = c-m
    float lmaxy = 0.f;
    for (int c = tid; c < WDIM; c += 256) {
        int m0 = c - (LDIM - 1); if (m0 < 0) m0 = 0;
        int m1 = c;              if (m1 > MDIM - 1) m1 = MDIM - 1;
        float acc = 0.f;
        for (int m = m0; m <= m1; ++m) {
            const int i = c - m;
            const float* p = s_in + m * LDIM;
            float v = 0.5f * p[i];
            if (i > 0)        v += 0.25f * p[i - 1];
            if (i < LDIM - 1) v += 0.25f * p[i + 1];
            acc += s_hs[m] * v;
        }
        s_y[c] = acc;
        y_out[(size_t)br * WDIM + c] = acc;
        lmaxy = fmaxf(lmaxy, acc);
    }
    __syncthreads();

    // Z[m,l] = Hs[m]*(0.25*y[m+l-1]*(l>0) + 0.5*y[m+l] + 0.25*y[m+l+1]*(l<30))
    float lmaxz = 0.f;
    for (int e = tid; e < ROW_IN; e += 256) {
        const int m = e / LDIM;
        const int l = e - m * LDIM;
        float v = 0.5f * s_y[m + l];
        if (l > 0)        v += 0.25f * s_y[m + l - 1];
        if (l < LDIM - 1) v += 0.25f * s_y[m + l + 1];
        lmaxz = fmaxf(lmaxz, v * s_hs[m]);
    }

    const float wy = wave_max(lmaxy);
    const float wz = wave_max(lmaxz);
    const int wave = tid >> 6, lane = tid & 63;
    if (lane == 0) { s_red[wave] = wy; s_red[4 + wave] = wz; }
    __syncthreads();
    if (tid == 0) {
        float my = fmaxf(fmaxf(s_red[0], s_red[1]), fmaxf(s_red[2], s_red[3]));
        float mz = fmaxf(fmaxf(s_red[4], s_red[5]), fmaxf(s_red[6], s_red[7]));
        atomicMax(&gmax[0], __float_as_uint(my));
        atomicMax(&gmax[1], __float_as_uint(mz));
    }
}

// One block per (b, r) row. Writes Xout (normalized Z), normalizes its own
// y row in place, and (b==0) writes Hs.
__global__ __launch_bounds__(256) void kB(const float* __restrict__ H,
                                          float* __restrict__ out,
                                          const unsigned int* __restrict__ gmax) {
    __shared__ float s_y[WDIM];
    __shared__ float s_hs[MDIM];

    const int br  = blockIdx.x;
    const int b   = br >> 9;
    const int r   = br & (MDIM - 1);
    const int tid = threadIdx.x;

    float* xout  = out;                                   // [NROWS][ROW_IN]
    float* yout  = out + (size_t)NROWS * ROW_IN;          // [NROWS][WDIM]
    float* hsout = yout + (size_t)NROWS * WDIM;           // [MDIM*MDIM]

    for (int t = tid; t < WDIM; t += 256) s_y[t] = yout[(size_t)br * WDIM + t];
    const float* hrow = H + (size_t)r * MDIM;
    for (int t = tid; t < MDIM; t += 256) s_hs[t] = sigmoid10(hrow[t]);
    __syncthreads();

    const float inv_my = 1.0f / __uint_as_float(gmax[0]);
    const float inv_mz = 1.0f / __uint_as_float(gmax[1]);

    // Xout row: float4 stores
    float4* xr4 = (float4*)(xout + (size_t)br * ROW_IN);
    for (int t4 = tid; t4 < ROW_IN / 4; t4 += 256) {
        const int e = t4 * 4;
        float vals[4];
        #pragma unroll
        for (int j = 0; j < 4; ++j) {
            const int idx = e + j;
            const int m = idx / LDIM;
            const int l = idx - m * LDIM;
            float v = 0.5f * s_y[m + l];
            if (l > 0)        v += 0.25f * s_y[m + l - 1];
            if (l < LDIM - 1) v += 0.25f * s_y[m + l + 1];
            vals[j] = v * s_hs[m] * inv_mz;
        }
        float4 o; o.x = vals[0]; o.y = vals[1]; o.z = vals[2]; o.w = vals[3];
        xr4[t4] = o;
    }

    // normalize own y row (this block is the only reader/writer of this row)
    for (int t = tid; t < WDIM; t += 256)
        yout[(size_t)br * WDIM + t] = s_y[t] * inv_my;

    // Hs output (once, by b==0 blocks)
    if (b == 0)
        for (int t = tid; t < MDIM; t += 256)
            hsout[(size_t)r * MDIM + t] = s_hs[t];
}

extern "C" void kernel_launch(void* const* d_in, const int* in_sizes, int n_in,
                              void* d_out, int out_size, void* d_ws, size_t ws_size,
                              hipStream_t stream) {
    const float* inp = (const float*)d_in[0];   // (4,512,512,31) f32
    const float* H   = (const float*)d_in[1];   // (1,512,512,1,1) f32
    float* out = (float*)d_out;
    unsigned int* gmax = (unsigned int*)d_ws;
    float* yraw = out + (size_t)NROWS * ROW_IN; // y slot, holds raw then normalized

    hipLaunchKernelGGL(kInit, dim3(1), dim3(64), 0, stream, gmax);
    hipLaunchKernelGGL(kA, dim3(NROWS), dim3(256), 0, stream, inp, H, yraw, gmax);
    hipLaunchKernelGGL(kB, dim3(NROWS), dim3(256), 0, stream, H, out, gmax);
}